// Round 1
// baseline (5863.975 us; speedup 1.0000x reference)
//
#include <hip/hip_runtime.h>

// ============================================================================
// 2-layer LSTM (B=64,T=512,D=256,H=1024) + linear, fp32.
// Persistent kernel, int16 weights/acts split into two int8 planes,
// 3x i8-MFMA per K=32, fragment-native h layout (R10), lag-2 diagonal (R11),
// one-hop subset polling (R12, proven 4.30ms).
// R13: XCD-L2 MULTICAST of the h-broadcast. R12 streamed every h fragment
//   with sc0 sc1 (MALL-direct) loads: 48MB of Infinity-Cache traffic per
//   phase (128 L0 WGs x 128KB + 128 L1 WGs x 256KB) = 5.7 TB/s implied --
//   the MALL fabric, not compute (MfmaUtil 12.9%), is the saturated pipe.
//   Fix: h fragment loads become ordinary cached loads (allocate in L1/L2),
//   and each poll is followed by an agent-scope acquire fence
//   (s_waitcnt + buffer_inv) so stale ring-slot lines from 4/8 phases ago
//   can never be served. After a successful poll the MALL copy is fresh
//   (producer slot stores are releases), so invalidate-then-load can only
//   refetch fresh data regardless of cross-CU interleaving. Each XCD now
//   pulls each h slot ~once from MALL and fans it out of its private L2
//   (34.5 TB/s aggregate) to its 32 CUs. Data path byte-identical to R12.
// ============================================================================

#define T_STEPS 512
#define NWG 256
#define LDS_W     131072                  // [64 ksteps][2 planes][64 lanes][16B]
#define LDS_GBUF  (64 * 33 * 4)           // 8448, padded stride 33
#define LDS_CBUF  (64 * 9 * 4)            // 2304, padded stride 9
#define LDS_OFFS  (32 * 4)
#define SMEM_BYTES (LDS_W + LDS_GBUF + LDS_CBUF + LDS_OFFS)   // 141952

typedef int v2i  __attribute__((ext_vector_type(2)));
typedef int v4i  __attribute__((ext_vector_type(4)));
typedef int v16i __attribute__((ext_vector_type(16)));

__device__ __forceinline__ v16i zero16() {
    v16i z;
#pragma unroll
    for (int i = 0; i < 16; ++i) z[i] = 0;
    return z;
}

// Agent-scope acquire: drains outstanding ops and invalidates this CU's L1 +
// this XCD's L2 so subsequent CACHED loads cannot hit stale ring-slot lines.
// Compiler lowers to s_waitcnt vmcnt(0) lgkmcnt(0); buffer_inv sc1 on gfx950.
__device__ __forceinline__ void acquire_inv() {
    __builtin_amdgcn_fence(__ATOMIC_ACQUIRE, "agent");
}

// One 8-kstep batch from fragment layout: 16 lane-contiguous dwordx4
// (CACHED: L1/L2-allocating -- XCD-L2 multicast; freshness guaranteed by the
// post-poll acquire_inv), NO trailing wait. kstep s at +s*2048, A0/A1 +0/+16.
__device__ __forceinline__ void load_f16_nw(const char* b0p, v4i* o) {
    const char* b1p = b0p + 4096;
    const char* b2p = b0p + 8192;
    const char* b3p = b0p + 12288;
    asm volatile(
        "global_load_dwordx4 %0, %16, off\n\t"
        "global_load_dwordx4 %1, %16, off offset:16\n\t"
        "global_load_dwordx4 %2, %16, off offset:2048\n\t"
        "global_load_dwordx4 %3, %16, off offset:2064\n\t"
        "global_load_dwordx4 %4, %17, off\n\t"
        "global_load_dwordx4 %5, %17, off offset:16\n\t"
        "global_load_dwordx4 %6, %17, off offset:2048\n\t"
        "global_load_dwordx4 %7, %17, off offset:2064\n\t"
        "global_load_dwordx4 %8, %18, off\n\t"
        "global_load_dwordx4 %9, %18, off offset:16\n\t"
        "global_load_dwordx4 %10, %18, off offset:2048\n\t"
        "global_load_dwordx4 %11, %18, off offset:2064\n\t"
        "global_load_dwordx4 %12, %19, off\n\t"
        "global_load_dwordx4 %13, %19, off offset:16\n\t"
        "global_load_dwordx4 %14, %19, off offset:2048\n\t"
        "global_load_dwordx4 %15, %19, off offset:2064"
        : "=&v"(o[0]), "=&v"(o[1]), "=&v"(o[2]), "=&v"(o[3]),
          "=&v"(o[4]), "=&v"(o[5]), "=&v"(o[6]), "=&v"(o[7]),
          "=&v"(o[8]), "=&v"(o[9]), "=&v"(o[10]), "=&v"(o[11]),
          "=&v"(o[12]), "=&v"(o[13]), "=&v"(o[14]), "=&v"(o[15])
        : "v"(b0p), "v"(b1p), "v"(b2p), "v"(b3p)
        : "memory");
}

#define WAIT_BIND(cntstr, b)                                                   \
    asm volatile("s_waitcnt vmcnt(" cntstr ")"                                 \
        : "+v"((b)[0]), "+v"((b)[1]), "+v"((b)[2]), "+v"((b)[3]),              \
          "+v"((b)[4]), "+v"((b)[5]), "+v"((b)[6]), "+v"((b)[7]),              \
          "+v"((b)[8]), "+v"((b)[9]), "+v"((b)[10]), "+v"((b)[11]),            \
          "+v"((b)[12]), "+v"((b)[13]), "+v"((b)[14]), "+v"((b)[15])           \
        :: "memory")

__device__ __forceinline__ void st16_wt(void* p, v4i v) {      // write-through MALL
    asm volatile("global_store_dwordx4 %0, %1, off sc0 sc1" :: "v"(p), "v"(v) : "memory");
}
__device__ __forceinline__ void store_slot(unsigned* p, unsigned v) {
    asm volatile("global_store_dword %0, %1, off sc0 sc1" :: "v"(p), "v"(v) : "memory");
}
__device__ __forceinline__ v4i ld4_mall(const unsigned* p) {
    v4i r;
    asm volatile("global_load_dwordx4 %0, %1, off sc0 sc1\n\ts_waitcnt vmcnt(0)"
                 : "=v"(r) : "v"(p) : "memory");
    return r;
}
__device__ __forceinline__ void waitcnt0() {
    asm volatile("s_waitcnt vmcnt(0)" ::: "memory");
}

__device__ __forceinline__ void split_a(v4i A0, v4i A1, v4i& HI, v4i& LO) {
    HI.x = (int)__builtin_amdgcn_perm((unsigned)A0.y, (unsigned)A0.x, 0x07050301u);
    HI.y = (int)__builtin_amdgcn_perm((unsigned)A0.w, (unsigned)A0.z, 0x07050301u);
    HI.z = (int)__builtin_amdgcn_perm((unsigned)A1.y, (unsigned)A1.x, 0x07050301u);
    HI.w = (int)__builtin_amdgcn_perm((unsigned)A1.w, (unsigned)A1.z, 0x07050301u);
    LO.x = (int)(__builtin_amdgcn_perm((unsigned)A0.y, (unsigned)A0.x, 0x06040200u) ^ 0x80808080u);
    LO.y = (int)(__builtin_amdgcn_perm((unsigned)A0.w, (unsigned)A0.z, 0x06040200u) ^ 0x80808080u);
    LO.z = (int)(__builtin_amdgcn_perm((unsigned)A1.y, (unsigned)A1.x, 0x06040200u) ^ 0x80808080u);
    LO.w = (int)(__builtin_amdgcn_perm((unsigned)A1.w, (unsigned)A1.z, 0x06040200u) ^ 0x80808080u);
}

__device__ __forceinline__ void consume8(const v4i* hb, const char* wbase,
                                         v16i& ahh, v16i& amid)
{
#pragma unroll
    for (int s = 0; s < 8; ++s) {
        v4i HI, LO; split_a(hb[2 * s], hb[2 * s + 1], HI, LO);
        v4i BH = *(const v4i*)(wbase + s * 2048);
        v4i BL = *(const v4i*)(wbase + s * 2048 + 1024);
        ahh  = __builtin_amdgcn_mfma_i32_32x32x32_i8(HI, BH, ahh, 0, 0, 0);
        amid = __builtin_amdgcn_mfma_i32_32x32x32_i8(HI, BL, amid, 0, 0, 0);
        amid = __builtin_amdgcn_mfma_i32_32x32x32_i8(LO, BH, amid, 0, 0, 0);
    }
}

// plain cached-load kstep (x segment only; xq stays row-major)
__device__ __forceinline__ void kstep(const short* __restrict__ ap,
                                      const char* __restrict__ wl,
                                      v16i& ahh, v16i& amid)
{
    v4i A0 = *(const v4i*)ap;
    v4i A1 = *(const v4i*)(ap + 8);
    v4i HI, LO; split_a(A0, A1, HI, LO);
    v4i BH = *(const v4i*)wl;
    v4i BL = *(const v4i*)(wl + 1024);
    ahh  = __builtin_amdgcn_mfma_i32_32x32x32_i8(HI, BH, ahh, 0, 0, 0);
    amid = __builtin_amdgcn_mfma_i32_32x32x32_i8(HI, BL, amid, 0, 0, 0);
    amid = __builtin_amdgcn_mfma_i32_32x32x32_i8(LO, BH, amid, 0, 0, 0);
}

// ---------------------------------------------------------------------------
__global__ void quant_x(const float* __restrict__ x, short* __restrict__ xq, int n)
{
    int i = blockIdx.x * 256 + threadIdx.x;
    if (i < n) {
        float v = x[i] * 2048.f;
        v = fminf(fmaxf(v, -32767.f), 32767.f);
        xq[i] = (short)__float2int_rn(v);
    }
}

// prep: quantize + gate-reorder + fragment-tile weights into per-WG LDS images.
__global__ void quant_w(const float* __restrict__ wih0, const float* __restrict__ whh0,
                        const float* __restrict__ wih1, const float* __restrict__ whh1,
                        char* __restrict__ wimg)
{
    int gid = blockIdx.x * 256 + threadIdx.x;       // 256*64*64 = 1048576 threads
    if (gid >= 256 * 64 * 64) return;
    int lane = gid & 63;
    int s    = (gid >> 6) & 63;
    int wg   = gid >> 12;
    int layer = wg >> 7, nblk = wg & 127;
    int col = nblk * 32 + (lane & 31);
    int ro  = (col & 3) * 1024 + (col >> 2);        // original gate-blocked row
    int k0  = s * 32 + (lane >> 5) * 16;
    char* dst = wimg + (size_t)wg * LDS_W + s * 2048 + lane * 16;
#pragma unroll
    for (int j = 0; j < 16; ++j) {
        int k = k0 + j;
        float w = 0.f;
        if (layer == 0) {
            if (k < 256)       w = wih0[ro * 256 + k];
            else if (k < 1280) w = whh0[ro * 1024 + (k - 256)];
        } else {
            if (k < 1024)      w = wih1[ro * 1024 + k];
            else               w = whh1[ro * 1024 + (k - 1024)];
        }
        int q  = __float2int_rn(w * 524288.f);      // 2^19, |q|<=16384
        int hi = (q + 128) >> 8;
        int lo = q - (hi << 8);
        dst[j]        = (char)hi;
        dst[1024 + j] = (char)lo;
    }
}

// ---------------------------------------------------------------------------
__global__ void __launch_bounds__(128) lstm_main(
    const short* __restrict__ xq, const char* __restrict__ wimg,
    const float* __restrict__ bih0, const float* __restrict__ bhh0,
    const float* __restrict__ bih1, const float* __restrict__ bhh1,
    short* __restrict__ h0q, short* __restrict__ h2q,
    float* __restrict__ h2f, unsigned* gslots)
{
    extern __shared__ char smem[];
    char*  wlds = smem;
    float* gbuf = (float*)(smem + LDS_W);                       // [64][33]
    float* cbuf = (float*)(smem + LDS_W + LDS_GBUF);            // [64][9]
    float* offs = (float*)(smem + LDS_W + LDS_GBUF + LDS_CBUF); // [32]

    const int wg    = blockIdx.x;
    const int layer = wg >> 7;
    const int nblk  = wg & 127;
    const int tid   = threadIdx.x;
    const int lane  = tid & 63;
    const int RB    = tid >> 6;                   // wave = rowblock
    const float inv30 = 9.313225746154785e-10f;   // 2^-30
    const float inv33 = 1.1641532182693481e-10f;  // 2^-33

    // stage this WG's weight image into LDS (128KB)
    {
        const v4i* src = (const v4i*)(wimg + (size_t)wg * LDS_W);
        v4i* dst = (v4i*)wlds;
        for (int i = tid; i < LDS_W / 16; i += 128) dst[i] = src[i];
    }
    for (int i = tid; i < 64 * 9; i += 128) cbuf[i] = 0.f;
    __syncthreads();

    // per-col constant: 128*colsum16*inv_scale (LO'=-128 bias comp) + gate bias
    if (tid < 32) {
        const int c  = tid;
        const int ns = (layer == 0) ? 40 : 64;
        int cs_x = 0, cs_h = 0;
        for (int s = 0; s < ns; ++s) {
            int sum = 0;
#pragma unroll
            for (int half = 0; half < 2; ++half) {
                const signed char* ph = (const signed char*)(wlds + s * 2048 + (half * 32 + c) * 16);
#pragma unroll
                for (int j = 0; j < 16; ++j)
                    sum += 256 * (int)ph[j] + (int)ph[1024 + j];
            }
            if (layer == 0 && s < 8) cs_x += sum; else cs_h += sum;
        }
        const int col = nblk * 32 + c;
        const int ro  = (col & 3) * 1024 + (col >> 2);
        const float bias = (layer == 0) ? (bih0[ro] + bhh0[ro]) : (bih1[ro] + bhh1[ro]);
        float off = 128.f * (float)cs_h * inv33 + bias;
        if (layer == 0) off += 128.f * (float)cs_x * inv30;
        offs[c] = off;
    }
    __syncthreads();

    const int mrow = RB * 32 + (lane & 31);           // batch row (x segment)
    const int ksub = (lane >> 5) * 16;                // k sub-offset (x segment)
    // producer store constants: units j0..j0+7, one 16B chunk per row
    const int j0   = nblk * 8;
    const int sj   = j0 >> 5;
    const int hbj  = (j0 >> 4) & 1;
    const int inj  = (j0 & 15) * 2;

    // phase p: L0 computes step p (p<T); L1 computes step p-2 (p>=2).
    for (int p = 0; p <= T_STEPS + 1; ++p) {
        const bool actL0 = (layer == 0) && (p < T_STEPS);
        const bool actL1 = (layer == 1) && (p >= 2);
        const bool active = actL0 || actL1;

        float px[16];
        v16i ahh = zero16(), amid = zero16();

        // ---- pre-poll work ------------------------------------------------
        if (actL0) {
            // x-projection for step p (no cross-WG dependency)
            v16i ax = zero16(), mx = zero16();
            const short* axp = xq + ((size_t)mrow * 512 + p) * 256 + ksub;
#pragma unroll
            for (int s = 0; s < 8; ++s)
                kstep(axp + s * 32, wlds + s * 2048 + lane * 16, ax, mx);
#pragma unroll
            for (int r = 0; r < 16; ++r)
                px[r] = ((float)ax[r] * 65536.f + (float)mx[r] * 256.f) * inv30;
        } else if (actL1) {
            // pre-guard: h0(p-2) visible once all L0 slots >= p-1 (L0 posts
            // value q+1 after storing h0(q); normally pre-satisfied).
            if (tid < 32) {
                const unsigned thr = (unsigned)(p - 1);
                const unsigned* sp = gslots + tid * 4;
                for (;;) {
                    v4i v = ld4_mall(sp);
                    bool ok = ((unsigned)v.x >= thr) && ((unsigned)v.y >= thr) &&
                              ((unsigned)v.z >= thr) && ((unsigned)v.w >= thr);
                    if (!__ballot(!ok)) break;
                    __builtin_amdgcn_s_sleep(3);
                }
            }
            __syncthreads();
            // acquire: slot observation happened-after producer release; wipe
            // possibly-stale L1/L2 copies of ring slot (p-2)&7 before CACHED
            // h0 loads. Executed per-wave so each wave's loads follow its own
            // buffer_inv in program order.
            acquire_inv();
            // hoisted h0(p-2) stream (weight ksteps 0..31)
            const char* f0 = (const char*)h0q + ((p - 2) & 7) * 131072
                           + RB * 65536 + lane * 32;
            v4i b0[16], b1[16];
            const char* W = wlds + lane * 16;
            load_f16_nw(f0, b0);
            load_f16_nw(f0 + 16384, b1);
            WAIT_BIND("16", b0); consume8(b0, W, ahh, amid);
            load_f16_nw(f0 + 32768, b0);
            WAIT_BIND("16", b1); consume8(b1, W + 8 * 2048, ahh, amid);
            load_f16_nw(f0 + 49152, b1);
            WAIT_BIND("16", b0); consume8(b0, W + 16 * 2048, ahh, amid);
            WAIT_BIND("0", b1);  consume8(b1, W + 24 * 2048, ahh, amid);
        }

        // ---- one-hop subset poll (gen p) ----------------------------------
        // L0: lanes 0-31 poll L0 slots >= p (RAW h0(p-1));
        //     lanes 32-63 poll L1 slots >= p-5 (WAR lag-guard, h0 ring=8).
        // L1: lanes 0-63 poll L1 slots >= p (RAW h2(p-3); WAR implied).
        if (p > 0) {
            if (tid < 64) {
                unsigned thr;
                const unsigned* sp;
                if (layer == 0) {
                    sp  = gslots + tid * 4;            // slots 0..255
                    thr = (tid < 32) ? (unsigned)p
                                     : (unsigned)(p > 5 ? p - 5 : 0);
                } else {
                    sp  = gslots + 128 + (tid & 31) * 4;  // L1 slots 128..255
                    thr = (unsigned)p;
                }
                for (;;) {
                    v4i v = ld4_mall(sp);
                    bool ok = ((unsigned)v.x >= thr) && ((unsigned)v.y >= thr) &&
                              ((unsigned)v.z >= thr) && ((unsigned)v.w >= thr);
                    if (!__ballot(!ok)) break;
                    __builtin_amdgcn_s_sleep(3);
                }
            }
            __syncthreads();
            // acquire for the post-poll CACHED streams (L0: h0(p-1) slot
            // (p-1)&7; L1: h2(p-3) slot (p-3)&3). The hoisted h0 data above
            // is already in registers, so wiping L2 here is safe.
            acquire_inv();
        }

        if (active) {
            float gates[16];
            v4i b0[16], b1[16];
            if (layer == 0) {
                // h0(p-1) stream (weight ksteps 8..39); h(-1)=0 -> skip at p=0
                if (p > 0) {
                    const char* f0 = (const char*)h0q + ((p - 1) & 7) * 131072
                                   + RB * 65536 + lane * 32;
                    const char* W = wlds + lane * 16;
                    load_f16_nw(f0, b0);
                    load_f16_nw(f0 + 16384, b1);
                    WAIT_BIND("16", b0); consume8(b0, W + 8 * 2048, ahh, amid);
                    load_f16_nw(f0 + 32768, b0);
                    WAIT_BIND("16", b1); consume8(b1, W + 16 * 2048, ahh, amid);
                    load_f16_nw(f0 + 49152, b1);
                    WAIT_BIND("16", b0); consume8(b0, W + 24 * 2048, ahh, amid);
                    WAIT_BIND("0", b1);  consume8(b1, W + 32 * 2048, ahh, amid);
                }
#pragma unroll
                for (int r = 0; r < 16; ++r)
                    gates[r] = px[r]
                             + ((float)ahh[r] * 65536.f + (float)amid[r] * 256.f) * inv33
                             + offs[lane & 31];
            } else {
                // h2(p-3) stream (weight ksteps 32..63); h2(-1)=0 -> skip p=2
                if (p > 2) {
                    const char* f2 = (const char*)h2q + ((p - 3) & 3) * 131072
                                   + RB * 65536 + lane * 32;
                    const char* W = wlds + lane * 16;
                    load_f16_nw(f2, b0);
                    load_f16_nw(f2 + 16384, b1);
                    WAIT_BIND("16", b0); consume8(b0, W + 32 * 2048, ahh, amid);
                    load_f16_nw(f2 + 32768, b0);
                    WAIT_BIND("16", b1); consume8(b1, W + 40 * 2048, ahh, amid);
                    load_f16_nw(f2 + 49152, b1);
                    WAIT_BIND("16", b0); consume8(b0, W + 48 * 2048, ahh, amid);
                    WAIT_BIND("0", b1);  consume8(b1, W + 56 * 2048, ahh, amid);
                }
#pragma unroll
                for (int r = 0; r < 16; ++r)
                    gates[r] = ((float)ahh[r] * 65536.f + (float)amid[r] * 256.f) * inv33
                             + offs[lane & 31];
            }
            // scatter C/D frag to LDS: col=lane&31, row=(r&3)+8*(r>>2)+4*(lane>>5)
            {
                const int rbase = RB * 32 + 4 * (lane >> 5);
                const int c = lane & 31;
#pragma unroll
                for (int r = 0; r < 16; ++r) {
                    int row = rbase + (r & 3) + 8 * (r >> 2);
                    gbuf[row * 33 + c] = gates[r];
                }
            }
        }
        __syncthreads();
        if (active && tid < 64) {
            // state update: thread = row, all 8 units; ONE 16B fragment store.
            const int r = tid;
            unsigned hq[8];
            float hf[8];
#pragma unroll
            for (int u = 0; u < 8; ++u) {
                const float gi = gbuf[r * 33 + 4 * u + 0];
                const float gf = gbuf[r * 33 + 4 * u + 1];
                const float gg = gbuf[r * 33 + 4 * u + 2];
                const float go = gbuf[r * 33 + 4 * u + 3];
                const float i_ = 1.f / (1.f + __expf(-gi));
                const float f_ = 1.f / (1.f + __expf(-gf));
                const float g_ = 1.f - 2.f / (__expf(2.f * gg) + 1.f);
                const float o_ = 1.f / (1.f + __expf(-go));
                float c_ = f_ * cbuf[r * 9 + u] + i_ * g_;
                cbuf[r * 9 + u] = c_;
                const float h_ = o_ * (1.f - 2.f / (__expf(2.f * c_) + 1.f));
                hq[u] = (unsigned)(unsigned short)(short)__float2int_rn(h_ * 16384.f);
                hf[u] = h_;
            }
            v4i pk;
            pk.x = (int)(hq[0] | (hq[1] << 16));
            pk.y = (int)(hq[2] | (hq[3] << 16));
            pk.z = (int)(hq[4] | (hq[5] << 16));
            pk.w = (int)(hq[6] | (hq[7] << 16));
            // L0 writes h0(p) slot p&7; L1 writes h2(p-2) slot (p-2)&3
            char* hw = (layer == 0)
                     ? (char*)h0q + (p & 7) * 131072
                     : (char*)h2q + ((p - 2) & 3) * 131072;
            hw += (r >> 5) * 65536 + sj * 2048 + ((r & 31) + 32 * hbj) * 32 + inj;
            st16_wt(hw, pk);
            if (layer == 1 && p == T_STEPS + 1) {
#pragma unroll
                for (int u = 0; u < 8; ++u) h2f[r * 1024 + j0 + u] = hf[u];
            }
        }
        // ---- arrival (value p+1, release: h stores drained first) ---------
        if (p < T_STEPS + 1) {
            waitcnt0();
            __syncthreads();
            if (tid == 0)
                store_slot(gslots + wg, (unsigned)(p + 1));
        }
    }
}

// ---------------------------------------------------------------------------
__global__ void final_lin(const float* __restrict__ h2f, const float* __restrict__ wlin,
                          const float* __restrict__ blin, float* __restrict__ out)
{
    const int b = blockIdx.x;
    const int l = threadIdx.x;
    float s = 0.f;
    for (int j = l; j < 1024; j += 64) s += h2f[b * 1024 + j] * wlin[j];
#pragma unroll
    for (int off = 32; off; off >>= 1) s += __shfl_down(s, off);
    if (l == 0) out[b] = s + blin[0];
}

// ---------------------------------------------------------------------------
extern "C" void kernel_launch(void* const* d_in, const int* in_sizes, int n_in,
                              void* d_out, int out_size, void* d_ws, size_t ws_size,
                              hipStream_t stream)
{
    const float* x    = (const float*)d_in[0];
    const float* wih0 = (const float*)d_in[1];
    const float* whh0 = (const float*)d_in[2];
    const float* bih0 = (const float*)d_in[3];
    const float* bhh0 = (const float*)d_in[4];
    const float* wih1 = (const float*)d_in[5];
    const float* whh1 = (const float*)d_in[6];
    const float* bih1 = (const float*)d_in[7];
    const float* bhh1 = (const float*)d_in[8];
    const float* wlin = (const float*)d_in[9];
    const float* blin = (const float*)d_in[10];

    // workspace layout
    char* ws = (char*)d_ws;
    unsigned* gslots = (unsigned*)ws;                    // 256 x 4B packed (16 lines)
    short* h0q = (short*)(ws + 65536);                   // [8 slots][128KB] fragment ring
    short* h2q = (short*)(ws + 65536 + 1048576);         // [4 slots][128KB] fragment ring
    float* h2f = (float*)(ws + 65536 + 1572864);         // [64][1024] f32 = 256KB
    short* xq  = (short*)(ws + 65536 + 1835008);         // 16MB
    char*  wimg = ws + 65536 + 1835008 + 16777216;       // 256 * 128KB = 32MB

    // zero arrival slots (h rings are written before any read)
    hipMemsetAsync(ws, 0, 65536, stream);

    quant_x<<<32768, 256, 0, stream>>>(x, xq, 64 * 512 * 256);
    quant_w<<<4096, 256, 0, stream>>>(wih0, whh0, wih1, whh1, wimg);

    hipFuncSetAttribute((const void*)lstm_main,
        hipFuncAttributeMaxDynamicSharedMemorySize, SMEM_BYTES);

    lstm_main<<<NWG, 128, SMEM_BYTES, stream>>>(xq, wimg, bih0, bhh0, bih1, bhh1,
                                                h0q, h2q, h2f, gslots);
    final_lin<<<64, 64, 0, stream>>>(h2f, wlin, blin, (float*)d_out);
}

// Round 4
// 4534.884 us; speedup vs baseline: 1.2931x; 1.2931x over previous
//
#include <hip/hip_runtime.h>

// ============================================================================
// 2-layer LSTM (B=64,T=512,D=256,H=1024) + linear, fp32.
// Persistent kernel, int16 weights/acts split into two int8 planes,
// 3x i8-MFMA per K=32, fragment-native h layout (R10), lag-2 diagonal (R11),
// one-hop subset polling (R12, proven 4.30ms).
// R13 (REVERTED): cached h loads + L2 invalidate self-defeated: 5.86ms.
// R14 (REVERTED): bundled 3 sync changes -> absmax 5e-2.
// R15 (REVERTED): isolated fused counted-vmcnt poll -> absmax 7e-4. Verdict:
//   the counted-poll fuse is empirically unsafe on this sync fabric; do not
//   retry. Sync structure is frozen at R12 (byte-identical below).
// R16: BATCH-ORDER ROTATION (pure data path, bit-identical numerics).
//   All 128 consumer WGs of a layer stream the same 128KB h-window in
//   lockstep in the same batch order -> the machine camps on a ~32KB span
//   of MALL banks at any instant; effective throughput collapses to the
//   per-bank service rate (measured 5.7TB/s implied, latency-plateau).
//   Fix: per-WG/per-wave rotation rot=(wg+2*RB)&3 of the 4-batch order in
//   each of the three h-streams, rotating the weight-kstep base together
//   with the fragment pointer. MFMA accumulation is exact int32 -> kstep
//   reorder is exactly associative -> output bit-identical to R12. Polls,
//   barriers, WAIT_BIND counts, arrivals: R12-exact.
// ============================================================================

#define T_STEPS 512
#define NWG 256
#define LDS_W     131072                  // [64 ksteps][2 planes][64 lanes][16B]
#define LDS_GBUF  (64 * 33 * 4)           // 8448, padded stride 33
#define LDS_CBUF  (64 * 9 * 4)            // 2304, padded stride 9
#define LDS_OFFS  (32 * 4)
#define SMEM_BYTES (LDS_W + LDS_GBUF + LDS_CBUF + LDS_OFFS)   // 141952

typedef int v2i  __attribute__((ext_vector_type(2)));
typedef int v4i  __attribute__((ext_vector_type(4)));
typedef int v16i __attribute__((ext_vector_type(16)));

__device__ __forceinline__ v16i zero16() {
    v16i z;
#pragma unroll
    for (int i = 0; i < 16; ++i) z[i] = 0;
    return z;
}

// One 8-kstep batch from fragment layout: 16 lane-contiguous dwordx4
// (sc0 sc1, MALL-direct), NO trailing wait. kstep s at +s*2048, A0/A1 +0/+16.
__device__ __forceinline__ void load_f16_nw(const char* b0p, v4i* o) {
    const char* b1p = b0p + 4096;
    const char* b2p = b0p + 8192;
    const char* b3p = b0p + 12288;
    asm volatile(
        "global_load_dwordx4 %0, %16, off sc0 sc1\n\t"
        "global_load_dwordx4 %1, %16, off offset:16 sc0 sc1\n\t"
        "global_load_dwordx4 %2, %16, off offset:2048 sc0 sc1\n\t"
        "global_load_dwordx4 %3, %16, off offset:2064 sc0 sc1\n\t"
        "global_load_dwordx4 %4, %17, off sc0 sc1\n\t"
        "global_load_dwordx4 %5, %17, off offset:16 sc0 sc1\n\t"
        "global_load_dwordx4 %6, %17, off offset:2048 sc0 sc1\n\t"
        "global_load_dwordx4 %7, %17, off offset:2064 sc0 sc1\n\t"
        "global_load_dwordx4 %8, %18, off sc0 sc1\n\t"
        "global_load_dwordx4 %9, %18, off offset:16 sc0 sc1\n\t"
        "global_load_dwordx4 %10, %18, off offset:2048 sc0 sc1\n\t"
        "global_load_dwordx4 %11, %18, off offset:2064 sc0 sc1\n\t"
        "global_load_dwordx4 %12, %19, off sc0 sc1\n\t"
        "global_load_dwordx4 %13, %19, off offset:16 sc0 sc1\n\t"
        "global_load_dwordx4 %14, %19, off offset:2048 sc0 sc1\n\t"
        "global_load_dwordx4 %15, %19, off offset:2064 sc0 sc1"
        : "=&v"(o[0]), "=&v"(o[1]), "=&v"(o[2]), "=&v"(o[3]),
          "=&v"(o[4]), "=&v"(o[5]), "=&v"(o[6]), "=&v"(o[7]),
          "=&v"(o[8]), "=&v"(o[9]), "=&v"(o[10]), "=&v"(o[11]),
          "=&v"(o[12]), "=&v"(o[13]), "=&v"(o[14]), "=&v"(o[15])
        : "v"(b0p), "v"(b1p), "v"(b2p), "v"(b3p)
        : "memory");
}

#define WAIT_BIND(cntstr, b)                                                   \
    asm volatile("s_waitcnt vmcnt(" cntstr ")"                                 \
        : "+v"((b)[0]), "+v"((b)[1]), "+v"((b)[2]), "+v"((b)[3]),              \
          "+v"((b)[4]), "+v"((b)[5]), "+v"((b)[6]), "+v"((b)[7]),              \
          "+v"((b)[8]), "+v"((b)[9]), "+v"((b)[10]), "+v"((b)[11]),            \
          "+v"((b)[12]), "+v"((b)[13]), "+v"((b)[14]), "+v"((b)[15])           \
        :: "memory")

__device__ __forceinline__ void st16_wt(void* p, v4i v) {      // write-through MALL
    asm volatile("global_store_dwordx4 %0, %1, off sc0 sc1" :: "v"(p), "v"(v) : "memory");
}
__device__ __forceinline__ void store_slot(unsigned* p, unsigned v) {
    asm volatile("global_store_dword %0, %1, off sc0 sc1" :: "v"(p), "v"(v) : "memory");
}
__device__ __forceinline__ v4i ld4_mall(const unsigned* p) {
    v4i r;
    asm volatile("global_load_dwordx4 %0, %1, off sc0 sc1\n\ts_waitcnt vmcnt(0)"
                 : "=v"(r) : "v"(p) : "memory");
    return r;
}
__device__ __forceinline__ void waitcnt0() {
    asm volatile("s_waitcnt vmcnt(0)" ::: "memory");
}

__device__ __forceinline__ void split_a(v4i A0, v4i A1, v4i& HI, v4i& LO) {
    HI.x = (int)__builtin_amdgcn_perm((unsigned)A0.y, (unsigned)A0.x, 0x07050301u);
    HI.y = (int)__builtin_amdgcn_perm((unsigned)A0.w, (unsigned)A0.z, 0x07050301u);
    HI.z = (int)__builtin_amdgcn_perm((unsigned)A1.y, (unsigned)A1.x, 0x07050301u);
    HI.w = (int)__builtin_amdgcn_perm((unsigned)A1.w, (unsigned)A1.z, 0x07050301u);
    LO.x = (int)(__builtin_amdgcn_perm((unsigned)A0.y, (unsigned)A0.x, 0x06040200u) ^ 0x80808080u);
    LO.y = (int)(__builtin_amdgcn_perm((unsigned)A0.w, (unsigned)A0.z, 0x06040200u) ^ 0x80808080u);
    LO.z = (int)(__builtin_amdgcn_perm((unsigned)A1.y, (unsigned)A1.x, 0x06040200u) ^ 0x80808080u);
    LO.w = (int)(__builtin_amdgcn_perm((unsigned)A1.w, (unsigned)A1.z, 0x06040200u) ^ 0x80808080u);
}

__device__ __forceinline__ void consume8(const v4i* hb, const char* wbase,
                                         v16i& ahh, v16i& amid)
{
#pragma unroll
    for (int s = 0; s < 8; ++s) {
        v4i HI, LO; split_a(hb[2 * s], hb[2 * s + 1], HI, LO);
        v4i BH = *(const v4i*)(wbase + s * 2048);
        v4i BL = *(const v4i*)(wbase + s * 2048 + 1024);
        ahh  = __builtin_amdgcn_mfma_i32_32x32x32_i8(HI, BH, ahh, 0, 0, 0);
        amid = __builtin_amdgcn_mfma_i32_32x32x32_i8(HI, BL, amid, 0, 0, 0);
        amid = __builtin_amdgcn_mfma_i32_32x32x32_i8(LO, BH, amid, 0, 0, 0);
    }
}

// rotated 4-batch stream: batches consumed in order rot, rot+1, rot+2, rot+3
// (mod 4). Exact-int accumulation => order-invariant, bit-identical output.
__device__ __forceinline__ void stream4_rot(const char* fbase, const char* wbase,
                                            int rot, v4i* b0, v4i* b1,
                                            v16i& ahh, v16i& amid)
{
    const char* fb[4];
    const char* wb[4];
#pragma unroll
    for (int i = 0; i < 4; ++i) {
        const int bsel = (rot + i) & 3;
        fb[i] = fbase + bsel * 16384;
        wb[i] = wbase + bsel * (8 * 2048);
    }
    load_f16_nw(fb[0], b0);
    load_f16_nw(fb[1], b1);
    WAIT_BIND("16", b0); consume8(b0, wb[0], ahh, amid);
    load_f16_nw(fb[2], b0);
    WAIT_BIND("16", b1); consume8(b1, wb[1], ahh, amid);
    load_f16_nw(fb[3], b1);
    WAIT_BIND("16", b0); consume8(b0, wb[2], ahh, amid);
    WAIT_BIND("0", b1);  consume8(b1, wb[3], ahh, amid);
}

// plain cached-load kstep (x segment only; xq stays row-major)
__device__ __forceinline__ void kstep(const short* __restrict__ ap,
                                      const char* __restrict__ wl,
                                      v16i& ahh, v16i& amid)
{
    v4i A0 = *(const v4i*)ap;
    v4i A1 = *(const v4i*)(ap + 8);
    v4i HI, LO; split_a(A0, A1, HI, LO);
    v4i BH = *(const v4i*)wl;
    v4i BL = *(const v4i*)(wl + 1024);
    ahh  = __builtin_amdgcn_mfma_i32_32x32x32_i8(HI, BH, ahh, 0, 0, 0);
    amid = __builtin_amdgcn_mfma_i32_32x32x32_i8(HI, BL, amid, 0, 0, 0);
    amid = __builtin_amdgcn_mfma_i32_32x32x32_i8(LO, BH, amid, 0, 0, 0);
}

// ---------------------------------------------------------------------------
__global__ void quant_x(const float* __restrict__ x, short* __restrict__ xq, int n)
{
    int i = blockIdx.x * 256 + threadIdx.x;
    if (i < n) {
        float v = x[i] * 2048.f;
        v = fminf(fmaxf(v, -32767.f), 32767.f);
        xq[i] = (short)__float2int_rn(v);
    }
}

// prep: quantize + gate-reorder + fragment-tile weights into per-WG LDS images.
__global__ void quant_w(const float* __restrict__ wih0, const float* __restrict__ whh0,
                        const float* __restrict__ wih1, const float* __restrict__ whh1,
                        char* __restrict__ wimg)
{
    int gid = blockIdx.x * 256 + threadIdx.x;       // 256*64*64 = 1048576 threads
    if (gid >= 256 * 64 * 64) return;
    int lane = gid & 63;
    int s    = (gid >> 6) & 63;
    int wg   = gid >> 12;
    int layer = wg >> 7, nblk = wg & 127;
    int col = nblk * 32 + (lane & 31);
    int ro  = (col & 3) * 1024 + (col >> 2);        // original gate-blocked row
    int k0  = s * 32 + (lane >> 5) * 16;
    char* dst = wimg + (size_t)wg * LDS_W + s * 2048 + lane * 16;
#pragma unroll
    for (int j = 0; j < 16; ++j) {
        int k = k0 + j;
        float w = 0.f;
        if (layer == 0) {
            if (k < 256)       w = wih0[ro * 256 + k];
            else if (k < 1280) w = whh0[ro * 1024 + (k - 256)];
        } else {
            if (k < 1024)      w = wih1[ro * 1024 + k];
            else               w = whh1[ro * 1024 + (k - 1024)];
        }
        int q  = __float2int_rn(w * 524288.f);      // 2^19, |q|<=16384
        int hi = (q + 128) >> 8;
        int lo = q - (hi << 8);
        dst[j]        = (char)hi;
        dst[1024 + j] = (char)lo;
    }
}

// ---------------------------------------------------------------------------
__global__ void __launch_bounds__(128) lstm_main(
    const short* __restrict__ xq, const char* __restrict__ wimg,
    const float* __restrict__ bih0, const float* __restrict__ bhh0,
    const float* __restrict__ bih1, const float* __restrict__ bhh1,
    short* __restrict__ h0q, short* __restrict__ h2q,
    float* __restrict__ h2f, unsigned* gslots)
{
    extern __shared__ char smem[];
    char*  wlds = smem;
    float* gbuf = (float*)(smem + LDS_W);                       // [64][33]
    float* cbuf = (float*)(smem + LDS_W + LDS_GBUF);            // [64][9]
    float* offs = (float*)(smem + LDS_W + LDS_GBUF + LDS_CBUF); // [32]

    const int wg    = blockIdx.x;
    const int layer = wg >> 7;
    const int nblk  = wg & 127;
    const int tid   = threadIdx.x;
    const int lane  = tid & 63;
    const int RB    = tid >> 6;                   // wave = rowblock
    const int rot   = (wg + 2 * RB) & 3;          // R16: per-WG/wave batch rotation
    const float inv30 = 9.313225746154785e-10f;   // 2^-30
    const float inv33 = 1.1641532182693481e-10f;  // 2^-33

    // stage this WG's weight image into LDS (128KB)
    {
        const v4i* src = (const v4i*)(wimg + (size_t)wg * LDS_W);
        v4i* dst = (v4i*)wlds;
        for (int i = tid; i < LDS_W / 16; i += 128) dst[i] = src[i];
    }
    for (int i = tid; i < 64 * 9; i += 128) cbuf[i] = 0.f;
    __syncthreads();

    // per-col constant: 128*colsum16*inv_scale (LO'=-128 bias comp) + gate bias
    if (tid < 32) {
        const int c  = tid;
        const int ns = (layer == 0) ? 40 : 64;
        int cs_x = 0, cs_h = 0;
        for (int s = 0; s < ns; ++s) {
            int sum = 0;
#pragma unroll
            for (int half = 0; half < 2; ++half) {
                const signed char* ph = (const signed char*)(wlds + s * 2048 + (half * 32 + c) * 16);
#pragma unroll
                for (int j = 0; j < 16; ++j)
                    sum += 256 * (int)ph[j] + (int)ph[1024 + j];
            }
            if (layer == 0 && s < 8) cs_x += sum; else cs_h += sum;
        }
        const int col = nblk * 32 + c;
        const int ro  = (col & 3) * 1024 + (col >> 2);
        const float bias = (layer == 0) ? (bih0[ro] + bhh0[ro]) : (bih1[ro] + bhh1[ro]);
        float off = 128.f * (float)cs_h * inv33 + bias;
        if (layer == 0) off += 128.f * (float)cs_x * inv30;
        offs[c] = off;
    }
    __syncthreads();

    const int mrow = RB * 32 + (lane & 31);           // batch row (x segment)
    const int ksub = (lane >> 5) * 16;                // k sub-offset (x segment)
    // producer store constants: units j0..j0+7, one 16B chunk per row
    const int j0   = nblk * 8;
    const int sj   = j0 >> 5;
    const int hbj  = (j0 >> 4) & 1;
    const int inj  = (j0 & 15) * 2;

    // phase p: L0 computes step p (p<T); L1 computes step p-2 (p>=2).
    for (int p = 0; p <= T_STEPS + 1; ++p) {
        const bool actL0 = (layer == 0) && (p < T_STEPS);
        const bool actL1 = (layer == 1) && (p >= 2);
        const bool active = actL0 || actL1;

        float px[16];
        v16i ahh = zero16(), amid = zero16();

        // ---- pre-poll work ------------------------------------------------
        if (actL0) {
            // x-projection for step p (no cross-WG dependency)
            v16i ax = zero16(), mx = zero16();
            const short* axp = xq + ((size_t)mrow * 512 + p) * 256 + ksub;
#pragma unroll
            for (int s = 0; s < 8; ++s)
                kstep(axp + s * 32, wlds + s * 2048 + lane * 16, ax, mx);
#pragma unroll
            for (int r = 0; r < 16; ++r)
                px[r] = ((float)ax[r] * 65536.f + (float)mx[r] * 256.f) * inv30;
        } else if (actL1) {
            // pre-guard: h0(p-2) visible once all L0 slots >= p-1 (L0 posts
            // value q+1 after storing h0(q); normally pre-satisfied).
            if (tid < 32) {
                const unsigned thr = (unsigned)(p - 1);
                const unsigned* sp = gslots + tid * 4;
                for (;;) {
                    v4i v = ld4_mall(sp);
                    bool ok = ((unsigned)v.x >= thr) && ((unsigned)v.y >= thr) &&
                              ((unsigned)v.z >= thr) && ((unsigned)v.w >= thr);
                    if (!__ballot(!ok)) break;
                    __builtin_amdgcn_s_sleep(3);
                }
            }
            __syncthreads();
            asm volatile("" ::: "memory");
            // hoisted h0(p-2) stream (weight ksteps 0..31), rotated batches
            const char* f0 = (const char*)h0q + ((p - 2) & 7) * 131072
                           + RB * 65536 + lane * 32;
            v4i b0[16], b1[16];
            waitcnt0();
            const char* W = wlds + lane * 16;
            stream4_rot(f0, W, rot, b0, b1, ahh, amid);
        }

        // ---- one-hop subset poll (gen p) ----------------------------------
        // L0: lanes 0-31 poll L0 slots >= p (RAW h0(p-1));
        //     lanes 32-63 poll L1 slots >= p-5 (WAR lag-guard, h0 ring=8).
        // L1: lanes 0-63 poll L1 slots >= p (RAW h2(p-3); WAR implied).
        if (p > 0) {
            if (tid < 64) {
                unsigned thr;
                const unsigned* sp;
                if (layer == 0) {
                    sp  = gslots + tid * 4;            // slots 0..255
                    thr = (tid < 32) ? (unsigned)p
                                     : (unsigned)(p > 5 ? p - 5 : 0);
                } else {
                    sp  = gslots + 128 + (tid & 31) * 4;  // L1 slots 128..255
                    thr = (unsigned)p;
                }
                for (;;) {
                    v4i v = ld4_mall(sp);
                    bool ok = ((unsigned)v.x >= thr) && ((unsigned)v.y >= thr) &&
                              ((unsigned)v.z >= thr) && ((unsigned)v.w >= thr);
                    if (!__ballot(!ok)) break;
                    __builtin_amdgcn_s_sleep(3);
                }
            }
            __syncthreads();
            asm volatile("" ::: "memory");
        }

        if (active) {
            float gates[16];
            v4i b0[16], b1[16];
            if (layer == 0) {
                // h0(p-1) stream (weight ksteps 8..39), rotated; skip at p=0
                if (p > 0) {
                    const char* f0 = (const char*)h0q + ((p - 1) & 7) * 131072
                                   + RB * 65536 + lane * 32;
                    waitcnt0();
                    const char* W = wlds + lane * 16;
                    stream4_rot(f0, W + 8 * 2048, rot, b0, b1, ahh, amid);
                }
#pragma unroll
                for (int r = 0; r < 16; ++r)
                    gates[r] = px[r]
                             + ((float)ahh[r] * 65536.f + (float)amid[r] * 256.f) * inv33
                             + offs[lane & 31];
            } else {
                // h2(p-3) stream (weight ksteps 32..63), rotated; skip p=2
                if (p > 2) {
                    const char* f2 = (const char*)h2q + ((p - 3) & 3) * 131072
                                   + RB * 65536 + lane * 32;
                    waitcnt0();
                    const char* W = wlds + lane * 16;
                    stream4_rot(f2, W + 32 * 2048, rot, b0, b1, ahh, amid);
                }
#pragma unroll
                for (int r = 0; r < 16; ++r)
                    gates[r] = ((float)ahh[r] * 65536.f + (float)amid[r] * 256.f) * inv33
                             + offs[lane & 31];
            }
            // scatter C/D frag to LDS: col=lane&31, row=(r&3)+8*(r>>2)+4*(lane>>5)
            {
                const int rbase = RB * 32 + 4 * (lane >> 5);
                const int c = lane & 31;
#pragma unroll
                for (int r = 0; r < 16; ++r) {
                    int row = rbase + (r & 3) + 8 * (r >> 2);
                    gbuf[row * 33 + c] = gates[r];
                }
            }
        }
        __syncthreads();
        if (active && tid < 64) {
            // state update: thread = row, all 8 units; ONE 16B fragment store.
            const int r = tid;
            unsigned hq[8];
            float hf[8];
#pragma unroll
            for (int u = 0; u < 8; ++u) {
                const float gi = gbuf[r * 33 + 4 * u + 0];
                const float gf = gbuf[r * 33 + 4 * u + 1];
                const float gg = gbuf[r * 33 + 4 * u + 2];
                const float go = gbuf[r * 33 + 4 * u + 3];
                const float i_ = 1.f / (1.f + __expf(-gi));
                const float f_ = 1.f / (1.f + __expf(-gf));
                const float g_ = 1.f - 2.f / (__expf(2.f * gg) + 1.f);
                const float o_ = 1.f / (1.f + __expf(-go));
                float c_ = f_ * cbuf[r * 9 + u] + i_ * g_;
                cbuf[r * 9 + u] = c_;
                const float h_ = o_ * (1.f - 2.f / (__expf(2.f * c_) + 1.f));
                hq[u] = (unsigned)(unsigned short)(short)__float2int_rn(h_ * 16384.f);
                hf[u] = h_;
            }
            v4i pk;
            pk.x = (int)(hq[0] | (hq[1] << 16));
            pk.y = (int)(hq[2] | (hq[3] << 16));
            pk.z = (int)(hq[4] | (hq[5] << 16));
            pk.w = (int)(hq[6] | (hq[7] << 16));
            // L0 writes h0(p) slot p&7; L1 writes h2(p-2) slot (p-2)&3
            char* hw = (layer == 0)
                     ? (char*)h0q + (p & 7) * 131072
                     : (char*)h2q + ((p - 2) & 3) * 131072;
            hw += (r >> 5) * 65536 + sj * 2048 + ((r & 31) + 32 * hbj) * 32 + inj;
            st16_wt(hw, pk);
            if (layer == 1 && p == T_STEPS + 1) {
#pragma unroll
                for (int u = 0; u < 8; ++u) h2f[r * 1024 + j0 + u] = hf[u];
            }
        }
        // ---- arrival (value p+1, release: h stores drained first) ---------
        if (p < T_STEPS + 1) {
            waitcnt0();
            __syncthreads();
            if (tid == 0)
                store_slot(gslots + wg, (unsigned)(p + 1));
        }
    }
}

// ---------------------------------------------------------------------------
__global__ void final_lin(const float* __restrict__ h2f, const float* __restrict__ wlin,
                          const float* __restrict__ blin, float* __restrict__ out)
{
    const int b = blockIdx.x;
    const int l = threadIdx.x;
    float s = 0.f;
    for (int j = l; j < 1024; j += 64) s += h2f[b * 1024 + j] * wlin[j];
#pragma unroll
    for (int off = 32; off; off >>= 1) s += __shfl_down(s, off);
    if (l == 0) out[b] = s + blin[0];
}

// ---------------------------------------------------------------------------
extern "C" void kernel_launch(void* const* d_in, const int* in_sizes, int n_in,
                              void* d_out, int out_size, void* d_ws, size_t ws_size,
                              hipStream_t stream)
{
    const float* x    = (const float*)d_in[0];
    const float* wih0 = (const float*)d_in[1];
    const float* whh0 = (const float*)d_in[2];
    const float* bih0 = (const float*)d_in[3];
    const float* bhh0 = (const float*)d_in[4];
    const float* wih1 = (const float*)d_in[5];
    const float* whh1 = (const float*)d_in[6];
    const float* bih1 = (const float*)d_in[7];
    const float* bhh1 = (const float*)d_in[8];
    const float* wlin = (const float*)d_in[9];
    const float* blin = (const float*)d_in[10];

    // workspace layout
    char* ws = (char*)d_ws;
    unsigned* gslots = (unsigned*)ws;                    // 256 x 4B packed (16 lines)
    short* h0q = (short*)(ws + 65536);                   // [8 slots][128KB] fragment ring
    short* h2q = (short*)(ws + 65536 + 1048576);         // [4 slots][128KB] fragment ring
    float* h2f = (float*)(ws + 65536 + 1572864);         // [64][1024] f32 = 256KB
    short* xq  = (short*)(ws + 65536 + 1835008);         // 16MB
    char*  wimg = ws + 65536 + 1835008 + 16777216;       // 256 * 128KB = 32MB

    // zero arrival slots (h rings are written before any read)
    hipMemsetAsync(ws, 0, 65536, stream);

    quant_x<<<32768, 256, 0, stream>>>(x, xq, 64 * 512 * 256);
    quant_w<<<4096, 256, 0, stream>>>(wih0, whh0, wih1, whh1, wimg);

    hipFuncSetAttribute((const void*)lstm_main,
        hipFuncAttributeMaxDynamicSharedMemorySize, SMEM_BYTES);

    lstm_main<<<NWG, 128, SMEM_BYTES, stream>>>(xq, wimg, bih0, bhh0, bih1, bhh1,
                                                h0q, h2q, h2f, gslots);
    final_lin<<<64, 64, 0, stream>>>(h2f, wlin, blin, (float*)d_out);
}

// Round 7
// 4393.937 us; speedup vs baseline: 1.3346x; 1.0321x over previous
//
#include <hip/hip_runtime.h>

// ============================================================================
// 2-layer LSTM (B=64,T=512,D=256,H=1024) + linear, fp32.
// Persistent kernel, int16 weights/acts split into two int8 planes,
// 3x i8-MFMA per K=32, fragment-native h layout (R10), lag-2 diagonal (R11),
// one-hop subset polling (R12, proven 4.30ms).
// R13 (REVERTED): cached h + L2 inv: 5.86ms.
// R14/R15 (REVERTED): counted-poll sync edits -> wrong results. BANNED.
// R16 (REVERTED): batch rotation: 4.53ms (lockstep same-line reads are GOOD).
// R17/R18 (REVERTED): L1 pair-split via new pbuf channel -> NaN (race not
//   statically locatable). RULE: cross-WG protocol frozen at R12 byte-for-byte.
// R19: INTRA-WG K-SPLIT (4 waves, 256 threads). Each phase's h-stream is a
//   serial latency chain (4 batches, ~2 MALL RTs); only 2 of 4 SIMDs were
//   occupied. Now waves (RB,kh), kh=0/1 each stream HALF the ksteps (2
//   batches) for their row-block; kh=1 publishes its int32 accumulators via
//   LDS; kh=0 adds (int-exact => math identical to R12) and proceeds to
//   gates/scatter. L0's x-projection merges as 8*ax into the int accumulator
//   (2^-30 = 8 * 2^-33, exact). Cross-WG polls/slots/rings/arrival:
//   R12-VERBATIM (wave 0 polls, barriers release the WG). Streams per wave
//   halve; the two L1 half-streams overlap across waves.
// ============================================================================

#define T_STEPS 512
#define NWG 256
#define LDS_W     131072                  // [64 ksteps][2 planes][64 lanes][16B]
#define LDS_GBUF  (64 * 33 * 4)           // 8448, padded stride 33
#define LDS_CBUF  (64 * 9 * 4)            // 2304, padded stride 9
#define LDS_OFFS  (32 * 4)
#define LDS_PEX   16384                   // [2 RB][32 vals][64 lanes] int
#define SMEM_BYTES (LDS_W + LDS_GBUF + LDS_CBUF + LDS_OFFS + LDS_PEX) // 158336

typedef int v4i  __attribute__((ext_vector_type(4)));
typedef int v16i __attribute__((ext_vector_type(16)));

__device__ __forceinline__ v16i zero16() {
    v16i z;
#pragma unroll
    for (int i = 0; i < 16; ++i) z[i] = 0;
    return z;
}

// One 8-kstep batch from fragment layout: 16 lane-contiguous dwordx4
// (sc0 sc1, MALL-direct), NO trailing wait. kstep s at +s*2048, A0/A1 +0/+16.
__device__ __forceinline__ void load_f16_nw(const char* b0p, v4i* o) {
    const char* b1p = b0p + 4096;
    const char* b2p = b0p + 8192;
    const char* b3p = b0p + 12288;
    asm volatile(
        "global_load_dwordx4 %0, %16, off sc0 sc1\n\t"
        "global_load_dwordx4 %1, %16, off offset:16 sc0 sc1\n\t"
        "global_load_dwordx4 %2, %16, off offset:2048 sc0 sc1\n\t"
        "global_load_dwordx4 %3, %16, off offset:2064 sc0 sc1\n\t"
        "global_load_dwordx4 %4, %17, off sc0 sc1\n\t"
        "global_load_dwordx4 %5, %17, off offset:16 sc0 sc1\n\t"
        "global_load_dwordx4 %6, %17, off offset:2048 sc0 sc1\n\t"
        "global_load_dwordx4 %7, %17, off offset:2064 sc0 sc1\n\t"
        "global_load_dwordx4 %8, %18, off sc0 sc1\n\t"
        "global_load_dwordx4 %9, %18, off offset:16 sc0 sc1\n\t"
        "global_load_dwordx4 %10, %18, off offset:2048 sc0 sc1\n\t"
        "global_load_dwordx4 %11, %18, off offset:2064 sc0 sc1\n\t"
        "global_load_dwordx4 %12, %19, off sc0 sc1\n\t"
        "global_load_dwordx4 %13, %19, off offset:16 sc0 sc1\n\t"
        "global_load_dwordx4 %14, %19, off offset:2048 sc0 sc1\n\t"
        "global_load_dwordx4 %15, %19, off offset:2064 sc0 sc1"
        : "=&v"(o[0]), "=&v"(o[1]), "=&v"(o[2]), "=&v"(o[3]),
          "=&v"(o[4]), "=&v"(o[5]), "=&v"(o[6]), "=&v"(o[7]),
          "=&v"(o[8]), "=&v"(o[9]), "=&v"(o[10]), "=&v"(o[11]),
          "=&v"(o[12]), "=&v"(o[13]), "=&v"(o[14]), "=&v"(o[15])
        : "v"(b0p), "v"(b1p), "v"(b2p), "v"(b3p)
        : "memory");
}

#define WAIT_BIND(cntstr, b)                                                   \
    asm volatile("s_waitcnt vmcnt(" cntstr ")"                                 \
        : "+v"((b)[0]), "+v"((b)[1]), "+v"((b)[2]), "+v"((b)[3]),              \
          "+v"((b)[4]), "+v"((b)[5]), "+v"((b)[6]), "+v"((b)[7]),              \
          "+v"((b)[8]), "+v"((b)[9]), "+v"((b)[10]), "+v"((b)[11]),            \
          "+v"((b)[12]), "+v"((b)[13]), "+v"((b)[14]), "+v"((b)[15])           \
        :: "memory")

__device__ __forceinline__ void st16_wt(void* p, v4i v) {      // write-through MALL
    asm volatile("global_store_dwordx4 %0, %1, off sc0 sc1" :: "v"(p), "v"(v) : "memory");
}
__device__ __forceinline__ void store_slot(unsigned* p, unsigned v) {
    asm volatile("global_store_dword %0, %1, off sc0 sc1" :: "v"(p), "v"(v) : "memory");
}
__device__ __forceinline__ v4i ld4_mall(const unsigned* p) {
    v4i r;
    asm volatile("global_load_dwordx4 %0, %1, off sc0 sc1\n\ts_waitcnt vmcnt(0)"
                 : "=v"(r) : "v"(p) : "memory");
    return r;
}
__device__ __forceinline__ void waitcnt0() {
    asm volatile("s_waitcnt vmcnt(0)" ::: "memory");
}
__device__ __forceinline__ bool slots_ok(v4i v, unsigned thr) {
    return ((unsigned)v.x >= thr) & ((unsigned)v.y >= thr) &
           ((unsigned)v.z >= thr) & ((unsigned)v.w >= thr);
}

__device__ __forceinline__ void split_a(v4i A0, v4i A1, v4i& HI, v4i& LO) {
    HI.x = (int)__builtin_amdgcn_perm((unsigned)A0.y, (unsigned)A0.x, 0x07050301u);
    HI.y = (int)__builtin_amdgcn_perm((unsigned)A0.w, (unsigned)A0.z, 0x07050301u);
    HI.z = (int)__builtin_amdgcn_perm((unsigned)A1.y, (unsigned)A1.x, 0x07050301u);
    HI.w = (int)__builtin_amdgcn_perm((unsigned)A1.w, (unsigned)A1.z, 0x07050301u);
    LO.x = (int)(__builtin_amdgcn_perm((unsigned)A0.y, (unsigned)A0.x, 0x06040200u) ^ 0x80808080u);
    LO.y = (int)(__builtin_amdgcn_perm((unsigned)A0.w, (unsigned)A0.z, 0x06040200u) ^ 0x80808080u);
    LO.z = (int)(__builtin_amdgcn_perm((unsigned)A1.y, (unsigned)A1.x, 0x06040200u) ^ 0x80808080u);
    LO.w = (int)(__builtin_amdgcn_perm((unsigned)A1.w, (unsigned)A1.z, 0x06040200u) ^ 0x80808080u);
}

__device__ __forceinline__ void consume8(const v4i* hb, const char* wbase,
                                         v16i& ahh, v16i& amid)
{
#pragma unroll
    for (int s = 0; s < 8; ++s) {
        v4i HI, LO; split_a(hb[2 * s], hb[2 * s + 1], HI, LO);
        v4i BH = *(const v4i*)(wbase + s * 2048);
        v4i BL = *(const v4i*)(wbase + s * 2048 + 1024);
        ahh  = __builtin_amdgcn_mfma_i32_32x32x32_i8(HI, BH, ahh, 0, 0, 0);
        amid = __builtin_amdgcn_mfma_i32_32x32x32_i8(HI, BL, amid, 0, 0, 0);
        amid = __builtin_amdgcn_mfma_i32_32x32x32_i8(LO, BH, amid, 0, 0, 0);
    }
}

// plain cached-load kstep (x segment only; xq stays row-major)
__device__ __forceinline__ void kstep(const short* __restrict__ ap,
                                      const char* __restrict__ wl,
                                      v16i& ahh, v16i& amid)
{
    v4i A0 = *(const v4i*)ap;
    v4i A1 = *(const v4i*)(ap + 8);
    v4i HI, LO; split_a(A0, A1, HI, LO);
    v4i BH = *(const v4i*)wl;
    v4i BL = *(const v4i*)(wl + 1024);
    ahh  = __builtin_amdgcn_mfma_i32_32x32x32_i8(HI, BH, ahh, 0, 0, 0);
    amid = __builtin_amdgcn_mfma_i32_32x32x32_i8(HI, BL, amid, 0, 0, 0);
    amid = __builtin_amdgcn_mfma_i32_32x32x32_i8(LO, BH, amid, 0, 0, 0);
}

// ---------------------------------------------------------------------------
__global__ void quant_x(const float* __restrict__ x, short* __restrict__ xq, int n)
{
    int i = blockIdx.x * 256 + threadIdx.x;
    if (i < n) {
        float v = x[i] * 2048.f;
        v = fminf(fmaxf(v, -32767.f), 32767.f);
        xq[i] = (short)__float2int_rn(v);
    }
}

// prep: quantize + gate-reorder + fragment-tile weights into per-WG LDS images.
__global__ void quant_w(const float* __restrict__ wih0, const float* __restrict__ whh0,
                        const float* __restrict__ wih1, const float* __restrict__ whh1,
                        char* __restrict__ wimg)
{
    int gid = blockIdx.x * 256 + threadIdx.x;       // 256*64*64 = 1048576 threads
    if (gid >= 256 * 64 * 64) return;
    int lane = gid & 63;
    int s    = (gid >> 6) & 63;
    int wg   = gid >> 12;
    int layer = wg >> 7, nblk = wg & 127;
    int col = nblk * 32 + (lane & 31);
    int ro  = (col & 3) * 1024 + (col >> 2);        // original gate-blocked row
    int k0  = s * 32 + (lane >> 5) * 16;
    char* dst = wimg + (size_t)wg * LDS_W + s * 2048 + lane * 16;
#pragma unroll
    for (int j = 0; j < 16; ++j) {
        int k = k0 + j;
        float w = 0.f;
        if (layer == 0) {
            if (k < 256)       w = wih0[ro * 256 + k];
            else if (k < 1280) w = whh0[ro * 1024 + (k - 256)];
        } else {
            if (k < 1024)      w = wih1[ro * 1024 + k];
            else               w = whh1[ro * 1024 + (k - 1024)];
        }
        int q  = __float2int_rn(w * 524288.f);      // 2^19, |q|<=16384
        int hi = (q + 128) >> 8;
        int lo = q - (hi << 8);
        dst[j]        = (char)hi;
        dst[1024 + j] = (char)lo;
    }
}

// ---------------------------------------------------------------------------
__global__ void __launch_bounds__(256, 1) lstm_main(
    const short* __restrict__ xq, const char* __restrict__ wimg,
    const float* __restrict__ bih0, const float* __restrict__ bhh0,
    const float* __restrict__ bih1, const float* __restrict__ bhh1,
    short* __restrict__ h0q, short* __restrict__ h2q,
    float* __restrict__ h2f, unsigned* gslots)
{
    extern __shared__ char smem[];
    char*  wlds = smem;
    float* gbuf = (float*)(smem + LDS_W);                       // [64][33]
    float* cbuf = (float*)(smem + LDS_W + LDS_GBUF);            // [64][9]
    float* offs = (float*)(smem + LDS_W + LDS_GBUF + LDS_CBUF); // [32]
    int*   pexch = (int*)(smem + LDS_W + LDS_GBUF + LDS_CBUF + LDS_OFFS);

    const int wg    = blockIdx.x;
    const int layer = wg >> 7;
    const int nblk  = wg & 127;
    const int tid   = threadIdx.x;
    const int lane  = tid & 63;
    const int w     = tid >> 6;                   // wave 0..3
    const int RB    = w >> 1;                     // rowblock (rows RB*32..)
    const int kh    = w & 1;                      // K-half of the streams
    const float inv33 = 1.1641532182693481e-10f;  // 2^-33

    // stage this WG's weight image into LDS (128KB)
    {
        const v4i* src = (const v4i*)(wimg + (size_t)wg * LDS_W);
        v4i* dst = (v4i*)wlds;
        for (int i = tid; i < LDS_W / 16; i += 256) dst[i] = src[i];
    }
    for (int i = tid; i < 64 * 9; i += 256) cbuf[i] = 0.f;
    __syncthreads();

    // per-col constant: 128*colsum16*inv_scale (LO'=-128 bias comp) + gate bias
    if (tid < 32) {
        const int c  = tid;
        const int ns = (layer == 0) ? 40 : 64;
        int cs_x = 0, cs_h = 0;
        for (int s = 0; s < ns; ++s) {
            int sum = 0;
#pragma unroll
            for (int half = 0; half < 2; ++half) {
                const signed char* ph = (const signed char*)(wlds + s * 2048 + (half * 32 + c) * 16);
#pragma unroll
                for (int j = 0; j < 16; ++j)
                    sum += 256 * (int)ph[j] + (int)ph[1024 + j];
            }
            if (layer == 0 && s < 8) cs_x += sum; else cs_h += sum;
        }
        const int col = nblk * 32 + c;
        const int ro  = (col & 3) * 1024 + (col >> 2);
        const float bias = (layer == 0) ? (bih0[ro] + bhh0[ro]) : (bih1[ro] + bhh1[ro]);
        float off = 128.f * (float)cs_h * inv33 + bias;
        if (layer == 0) off += 128.f * (float)cs_x * 9.313225746154785e-10f; // 2^-30
        offs[c] = off;
    }
    __syncthreads();

    const int mrow = RB * 32 + (lane & 31);           // batch row (x segment)
    const int ksub = (lane >> 5) * 16;                // k sub-offset (x segment)
    // producer store constants: units j0..j0+7, one 16B chunk per row
    const int j0   = nblk * 8;
    const int sj   = j0 >> 5;
    const int hbj  = (j0 >> 4) & 1;
    const int inj  = (j0 & 15) * 2;

    // phase p: L0 computes step p (p<T); L1 computes step p-2 (p>=2).
    for (int p = 0; p <= T_STEPS + 1; ++p) {
        const bool actL0 = (layer == 0) && (p < T_STEPS);
        const bool actL1 = (layer == 1) && (p >= 2);
        const bool active = actL0 || actL1;

        v16i ahh = zero16(), amid = zero16();

        if (layer == 0) {
            // x-projection (kh==0 wave; cached loads; pre-poll) ------------
            v16i ax = zero16(), mx = zero16();
            if (actL0 && kh == 0) {
                const short* axp = xq + ((size_t)mrow * 512 + p) * 256 + ksub;
#pragma unroll
                for (int s = 0; s < 8; ++s)
                    kstep(axp + s * 32, wlds + s * 2048 + lane * 16, ax, mx);
            }
            // main poll [R12-verbatim]: wave0 lanes 0-31 L0>=p (RAW h0(p-1));
            // lanes 32-63 L1>=p-5 (WAR lag-guard, h0 ring=8).
            if (p > 0) {
                if (tid < 64) {
                    const unsigned thr = (tid < 32) ? (unsigned)p
                                                    : (unsigned)(p > 5 ? p - 5 : 0);
                    const unsigned* sp = gslots + tid * 4;
                    for (;;) {
                        v4i v = ld4_mall(sp);
                        if (!__ballot(!slots_ok(v, thr))) break;
                        __builtin_amdgcn_s_sleep(3);
                    }
                }
                __syncthreads();
                asm volatile("" ::: "memory");
            }
            // h0(p-1) half-stream (weight ksteps 8..39, kh half); skip p=0
            if (actL0 && p > 0) {
                const char* f0 = (const char*)h0q + ((p - 1) & 7) * 131072
                               + RB * 65536 + lane * 32 + kh * 32768;
                const char* W = wlds + lane * 16 + (8 + kh * 16) * 2048;
                v4i b0[16], b1[16];
                waitcnt0();
                load_f16_nw(f0, b0);
                load_f16_nw(f0 + 16384, b1);
                WAIT_BIND("16", b0); consume8(b0, W, ahh, amid);
                WAIT_BIND("0", b1);  consume8(b1, W + 8 * 2048, ahh, amid);
            }
            // merge x-projection (2^-30 = 8 * 2^-33; int-exact, no overflow:
            // |8*ax|<=33M, |8*mx|<=66M, h-part <=25M, all << 2^31)
            if (actL0 && kh == 0) {
#pragma unroll
                for (int r = 0; r < 16; ++r) {
                    ahh[r]  += 8 * ax[r];
                    amid[r] += 8 * mx[r];
                }
            }
        } else {
            if (actL1) {
                // pre-guard [R12-verbatim]: h0(p-2) visible once L0 >= p-1
                if (tid < 32) {
                    const unsigned thr = (unsigned)(p - 1);
                    const unsigned* sp = gslots + tid * 4;
                    for (;;) {
                        v4i v = ld4_mall(sp);
                        if (!__ballot(!slots_ok(v, thr))) break;
                        __builtin_amdgcn_s_sleep(3);
                    }
                }
                __syncthreads();
                asm volatile("" ::: "memory");
                // hoisted h0(p-2) half-stream (weight ksteps 0..31, kh half)
                const char* f0 = (const char*)h0q + ((p - 2) & 7) * 131072
                               + RB * 65536 + lane * 32 + kh * 32768;
                const char* W = wlds + lane * 16 + kh * 16 * 2048;
                v4i b0[16], b1[16];
                waitcnt0();
                load_f16_nw(f0, b0);
                load_f16_nw(f0 + 16384, b1);
                WAIT_BIND("16", b0); consume8(b0, W, ahh, amid);
                WAIT_BIND("0", b1);  consume8(b1, W + 8 * 2048, ahh, amid);
            }
            // main poll [R12-verbatim]: L1 slots >= p (RAW h2(p-3))
            if (p > 0) {
                if (tid < 64) {
                    const unsigned* sp = gslots + 128 + (tid & 31) * 4;
                    const unsigned thr = (unsigned)p;
                    for (;;) {
                        v4i v = ld4_mall(sp);
                        if (!__ballot(!slots_ok(v, thr))) break;
                        __builtin_amdgcn_s_sleep(3);
                    }
                }
                __syncthreads();
                asm volatile("" ::: "memory");
            }
            // h2(p-3) half-stream (weight ksteps 32..63, kh half); skip p<=2
            if (actL1 && p > 2) {
                const char* f2 = (const char*)h2q + ((p - 3) & 3) * 131072
                               + RB * 65536 + lane * 32 + kh * 32768;
                const char* W = wlds + lane * 16 + (32 + kh * 16) * 2048;
                v4i b0[16], b1[16];
                waitcnt0();
                load_f16_nw(f2, b0);
                load_f16_nw(f2 + 16384, b1);
                WAIT_BIND("16", b0); consume8(b0, W, ahh, amid);
                WAIT_BIND("0", b1);  consume8(b1, W + 8 * 2048, ahh, amid);
            }
        }

        // ---- K-half exchange (int-exact): kh1 publishes, kh0 combines -----
        if (active && kh == 1) {
            int* pxm = pexch + RB * 2048;
#pragma unroll
            for (int i = 0; i < 16; ++i) pxm[i * 64 + lane] = ahh[i];
#pragma unroll
            for (int i = 0; i < 16; ++i) pxm[(16 + i) * 64 + lane] = amid[i];
        }
        __syncthreads();
        if (active && kh == 0) {
            const int* pxm = pexch + RB * 2048;
            const int rbase = RB * 32 + 4 * (lane >> 5);
            const int c = lane & 31;
#pragma unroll
            for (int r = 0; r < 16; ++r) {
                int th = ahh[r]  + pxm[r * 64 + lane];
                int tm = amid[r] + pxm[(16 + r) * 64 + lane];
                float g = ((float)th * 65536.f + (float)tm * 256.f) * inv33
                        + offs[c];
                int row = rbase + (r & 3) + 8 * (r >> 2);
                gbuf[row * 33 + c] = g;
            }
        }
        __syncthreads();
        if (active && tid < 64) {
            // state update [R12-verbatim]: thread = row, 8 units, ONE 16B store
            const int r = tid;
            unsigned hq[8];
            float hf[8];
#pragma unroll
            for (int u = 0; u < 8; ++u) {
                const float gi = gbuf[r * 33 + 4 * u + 0];
                const float gf = gbuf[r * 33 + 4 * u + 1];
                const float gg = gbuf[r * 33 + 4 * u + 2];
                const float go = gbuf[r * 33 + 4 * u + 3];
                const float i_ = 1.f / (1.f + __expf(-gi));
                const float f_ = 1.f / (1.f + __expf(-gf));
                const float g_ = 1.f - 2.f / (__expf(2.f * gg) + 1.f);
                const float o_ = 1.f / (1.f + __expf(-go));
                float c_ = f_ * cbuf[r * 9 + u] + i_ * g_;
                cbuf[r * 9 + u] = c_;
                const float h_ = o_ * (1.f - 2.f / (__expf(2.f * c_) + 1.f));
                hq[u] = (unsigned)(unsigned short)(short)__float2int_rn(h_ * 16384.f);
                hf[u] = h_;
            }
            v4i pk;
            pk.x = (int)(hq[0] | (hq[1] << 16));
            pk.y = (int)(hq[2] | (hq[3] << 16));
            pk.z = (int)(hq[4] | (hq[5] << 16));
            pk.w = (int)(hq[6] | (hq[7] << 16));
            // L0 writes h0(p) slot p&7; L1 writes h2(p-2) slot (p-2)&3
            char* hw = (layer == 0)
                     ? (char*)h0q + (p & 7) * 131072
                     : (char*)h2q + ((p - 2) & 3) * 131072;
            hw += (r >> 5) * 65536 + sj * 2048 + ((r & 31) + 32 * hbj) * 32 + inj;
            st16_wt(hw, pk);
            if (layer == 1 && p == T_STEPS + 1) {
#pragma unroll
                for (int u = 0; u < 8; ++u) h2f[r * 1024 + j0 + u] = hf[u];
            }
        }
        // ---- arrival [R12-verbatim] (value p+1, release) ------------------
        if (p < T_STEPS + 1) {
            waitcnt0();
            __syncthreads();
            if (tid == 0)
                store_slot(gslots + wg, (unsigned)(p + 1));
        }
    }
}

// ---------------------------------------------------------------------------
__global__ void final_lin(const float* __restrict__ h2f, const float* __restrict__ wlin,
                          const float* __restrict__ blin, float* __restrict__ out)
{
    const int b = blockIdx.x;
    const int l = threadIdx.x;
    float s = 0.f;
    for (int j = l; j < 1024; j += 64) s += h2f[b * 1024 + j] * wlin[j];
#pragma unroll
    for (int off = 32; off; off >>= 1) s += __shfl_down(s, off);
    if (l == 0) out[b] = s + blin[0];
}

// ---------------------------------------------------------------------------
extern "C" void kernel_launch(void* const* d_in, const int* in_sizes, int n_in,
                              void* d_out, int out_size, void* d_ws, size_t ws_size,
                              hipStream_t stream)
{
    const float* x    = (const float*)d_in[0];
    const float* wih0 = (const float*)d_in[1];
    const float* whh0 = (const float*)d_in[2];
    const float* bih0 = (const float*)d_in[3];
    const float* bhh0 = (const float*)d_in[4];
    const float* wih1 = (const float*)d_in[5];
    const float* whh1 = (const float*)d_in[6];
    const float* bih1 = (const float*)d_in[7];
    const float* bhh1 = (const float*)d_in[8];
    const float* wlin = (const float*)d_in[9];
    const float* blin = (const float*)d_in[10];

    // workspace layout [R12-verbatim]
    char* ws = (char*)d_ws;
    unsigned* gslots = (unsigned*)ws;                    // 256 x 4B packed (16 lines)
    short* h0q = (short*)(ws + 65536);                   // [8 slots][128KB] fragment ring
    short* h2q = (short*)(ws + 65536 + 1048576);         // [4 slots][128KB] fragment ring
    float* h2f = (float*)(ws + 65536 + 1572864);         // [64][1024] f32 = 256KB
    short* xq  = (short*)(ws + 65536 + 1835008);         // 16MB
    char*  wimg = ws + 65536 + 1835008 + 16777216;       // 256 * 128KB = 32MB

    // zero arrival slots (h rings are written before any read)
    hipMemsetAsync(ws, 0, 65536, stream);

    quant_x<<<32768, 256, 0, stream>>>(x, xq, 64 * 512 * 256);
    quant_w<<<4096, 256, 0, stream>>>(wih0, whh0, wih1, whh1, wimg);

    hipFuncSetAttribute((const void*)lstm_main,
        hipFuncAttributeMaxDynamicSharedMemorySize, SMEM_BYTES);

    lstm_main<<<NWG, 256, SMEM_BYTES, stream>>>(xq, wimg, bih0, bhh0, bih1, bhh1,
                                                h0q, h2q, h2f, gslots);
    final_lin<<<64, 64, 0, stream>>>(h2f, wlin, blin, (float*)d_out);
}